// Round 13
// baseline (116.250 us; speedup 1.0000x reference)
//
#include <hip/hip_runtime.h>
#include <hip/hip_bf16.h>
#include <math.h>

typedef short short8 __attribute__((ext_vector_type(8)));
typedef short short4v __attribute__((ext_vector_type(4)));
typedef float f32x4 __attribute__((ext_vector_type(4)));
typedef float f32x16 __attribute__((ext_vector_type(16)));
typedef unsigned int uint4v __attribute__((ext_vector_type(4)));
typedef unsigned short u16;

constexpr int TN = 4096;    // sequence
constexpr int CN = 32;      // embed
constexpr int HN = 64;      // head size
constexpr int QT = 128;     // q rows per block (4 waves x 32)
constexpr int KT = 64;      // keys per tile
constexpr int NQ = TN / QT; // 32 q-tiles per batch
constexpr int BN = 16;      // batch
constexpr size_t BT  = (size_t)BN * TN;
constexpr size_t BTH = BT * (size_t)HN;
constexpr float SCL = 0.18033688011112042f;  // 0.125 * log2(e), folded into q

__device__ __forceinline__ u16 f2bf(float f) {
    return __builtin_bit_cast(u16, __float2bfloat16(f));
}
__device__ __forceinline__ float bf2f(u16 v) {
    return __builtin_bit_cast(float, (unsigned)v << 16);
}
// HW packed f32->bf16 (RNE), src0 -> low half
__device__ __forceinline__ unsigned cvtpk(float lo, float hi) {
    unsigned r;
    asm("v_cvt_pk_bf16_f32 %0, %1, %2" : "=v"(r) : "v"(lo), "v"(hi));
    return r;
}
__device__ __forceinline__ float ex2(float x) {
#if __has_builtin(__builtin_amdgcn_exp2f)
    return __builtin_amdgcn_exp2f(x);   // raw v_exp_f32; exp2(-inf)=0
#else
    return exp2f(x);
#endif
}
// async global->LDS, 16B/lane, LDS dest = wave-uniform base + lane*16
typedef const __attribute__((address_space(1))) unsigned gu32;
typedef __attribute__((address_space(3))) unsigned lu32;
__device__ __forceinline__ void gll16(const u16* g, u16* l) {
    __builtin_amdgcn_global_load_lds((gu32*)(const void*)g, (lu32*)(void*)l, 16, 0, 0);
}

// ---------------------------------------------------------------------------
// Kernel 1: fused QKV projection -> bf16.  BYTE-IDENTICAL to green R12/R8.
// q PRE-SCALED by 0.125*log2(e).  q,k row-major; v transposed vt[b][h][t]
// (natural key order -- NO layout permutation).
// ---------------------------------------------------------------------------
__global__ __launch_bounds__(256) void qkv_proj(
    const float* __restrict__ x,
    const float* __restrict__ Wk,
    const float* __restrict__ Wq,
    const float* __restrict__ Wv,
    u16* __restrict__ qb, u16* __restrict__ kb, u16* __restrict__ vtb)
{
    __shared__ float sW[3][CN * HN];   // 24 KB: 0=q, 1=k, 2=v

    const int tid = threadIdx.x;
#pragma unroll
    for (int i = 0; i < 8; ++i) {
        const int idx = i * 256 + tid;   // 0..2047
        sW[0][idx] = Wq[idx];
        sW[1][idx] = Wk[idx];
        sW[2][idx] = Wv[idx];
    }
    __syncthreads();

    const int gid  = blockIdx.x * 256 + tid;   // 0 .. 4*B*T-1
    const int row  = gid >> 2;                 // b*T + t
    const int qq   = gid & 3;                  // h-quarter
    const int h0   = qq * 16;
    const int b    = row >> 12;                // T = 4096
    const int tloc = row & (TN - 1);
    const float* xr = x + (size_t)row * CN;

    float xv[CN];
#pragma unroll
    for (int cc = 0; cc < CN; cc += 4) {
        f32x4 t4 = *reinterpret_cast<const f32x4*>(xr + cc);
        xv[cc] = t4[0]; xv[cc + 1] = t4[1]; xv[cc + 2] = t4[2]; xv[cc + 3] = t4[3];
    }

    float aq[16], ak[16], av[16];
#pragma unroll
    for (int j = 0; j < 16; ++j) { aq[j] = 0.f; ak[j] = 0.f; av[j] = 0.f; }

#pragma unroll
    for (int cc = 0; cc < CN; ++cc) {
        const float xc = xv[cc];
        const float* wq = &sW[0][cc * HN + h0];
        const float* wk = &sW[1][cc * HN + h0];
        const float* wv = &sW[2][cc * HN + h0];
#pragma unroll
        for (int j = 0; j < 16; ++j) {
            aq[j] += xc * wq[j];
            ak[j] += xc * wk[j];
            av[j] += xc * wv[j];
        }
    }

    u16* qo = qb + (size_t)row * HN + h0;
    u16* ko = kb + (size_t)row * HN + h0;
#pragma unroll
    for (int v8 = 0; v8 < 2; ++v8) {
        short8 pq, pk;
#pragma unroll
        for (int j = 0; j < 8; ++j) {
            pq[j] = (short)f2bf(aq[v8 * 8 + j] * SCL);   // fold softmax scale
            pk[j] = (short)f2bf(ak[v8 * 8 + j]);
        }
        *reinterpret_cast<short8*>(qo + v8 * 8) = pq;
        *reinterpret_cast<short8*>(ko + v8 * 8) = pk;
    }
#pragma unroll
    for (int j = 0; j < 16; ++j)
        vtb[((size_t)b * HN + h0 + j) * TN + tloc] = f2bf(av[j]);
}

// ---------------------------------------------------------------------------
// Kernel 2: causal flash attention, 32x32x16 bf16 MFMA, fixed-zero-max
// softmax, NSPLIT-way K-split, LPT heavy-first 1-D grid.
// R12 structure with TWO deltas:
//  (1) SHUFFLE-FREE PV via dual-b64 A-reads, natural V layout:
//      shared slot->key map kappa(j,h) = 16ks + 8*(j>>2) + 4h + (j&3).
//      B-frag = lane's OWN wpk words in register order (kappa-consistent:
//      own p[8*s2i+j] has key 16ks+8(j>>2)+4h+(j&3)).  A-frag = two
//      ds_read_b64 chunks of the UNCHANGED swizzled V^T tile: granule
//      (2ks+g'), byte sub-offset 8h -> keys 16ks+8g'+4h..+3, g'=0,1.
//      A and B share kappa -> sigma-invariant correct (two prior working
//      conventions prove operand-map symmetry).  Deletes 8 bpermute +
//      24 cndmask per tile; qkv/DMA byte-identical to green R12.
//  (2) launch_bounds(256,5): LDS 32KB allows exactly 5 blocks/CU ->
//      20 waves/CU.  Reg headroom from deleted rx[] (-8 VGPR).
//      Spill signature if wrong: FETCH_SIZE blow-up (R6 fingerprint).
// ---------------------------------------------------------------------------
template<int NSPLIT>
__global__ __launch_bounds__(256, 5) void attn_mfma(
    const u16* __restrict__ qb,
    const u16* __restrict__ kb,
    const u16* __restrict__ vtb,
    u16* __restrict__ pO,
    float* __restrict__ lseb)
{
    __shared__ __align__(16) u16 smem[16384];   // 32 KB: buf b at b*8192 (K|Vt)
    float* ep = (float*)smem;                   // epilogue [64][64] f32 (16 KB)

    const int tid  = threadIdx.x;
    const int lane = tid & 63;
    const int w    = tid >> 6;
    const int c    = lane & 31;
    const int h    = lane >> 5;

    // LPT heavy-first mapping: idx 0.. -> qt NQ-1 .. 0
    const int idx = blockIdx.x;
    const int qt  = NQ - 1 - idx / (BN * NSPLIT);
    const int sub = idx % (BN * NSPLIT);
    const int b   = sub / NSPLIT;
    const int par = sub % NSPLIT;

    const int qbase = qt * QT;
    const int wq    = qbase + w * 32;
    const int qg    = wq + c;          // this lane's q row

    const u16* Qg = qb  + (size_t)b * TN * HN;
    const u16* Kg = kb  + (size_t)b * TN * HN;
    const u16* Vg = vtb + (size_t)b * HN * TN;

    // Q fragments: qh[dd] = Q[qg][(2*dd+h)*8 .. +7]
    short8 qh[4];
#pragma unroll
    for (int dd = 0; dd < 4; ++dd)
        qh[dd] = *reinterpret_cast<const short8*>(
            Qg + (size_t)qg * HN + (2 * dd + h) * 8);

    f32x16 oT[2];                      // O^T acc: col=q=c (lane-local)
#pragma unroll
    for (int dh = 0; dh < 2; ++dh)
#pragma unroll
        for (int j = 0; j < 16; ++j) oT[dh][j] = 0.f;
    float lsum = 0.f;

    const int nt = 2 * qt + 2;

    // ---- global_load_lds source pointers (pre-swizzled column) ----
    const int rw  = lane >> 3;                       // 0..7
    const int gsw = (lane & 7) ^ rw;                 // pre-swizzled granule
    const u16* kq  = Kg + (size_t)(par * KT + 16 * w + rw) * HN + gsw * 8;
    const u16* vq  = Vg + (size_t)(16 * w + rw) * TN + par * KT + gsw * 8;
    const u16* vq2 = vq + (size_t)8 * TN;
    const size_t kinc = (size_t)NSPLIT * KT * HN;    // u16 elements
    const size_t vinc = (size_t)NSPLIT * KT;

    // prologue: stage first tile into buf 0
    {
        u16* Kd = smem + w * 1024;
        u16* Vd = Kd + 4096;
        gll16(kq,        Kd);        gll16(kq + 512,  Kd + 512);
        gll16(vq,        Vd);        gll16(vq2,       Vd + 512);
    }

    int cur = 0;
    for (int t = par; t < nt; t += NSPLIT) {
        const int kbase = t * KT;

        __syncthreads();   // vmcnt drained -> buf[cur] ready; prev compute done
        u16* Ksb = smem + cur * 8192;
        u16* Vtb = Ksb + 4096;

        // prefetch next residue-tile into the other buffer
        if (t + NSPLIT < nt) {
            kq += kinc; vq += vinc; vq2 += vinc;
            u16* Kd = smem + (cur ^ 1) * 8192 + w * 1024;
            u16* Vd = Kd + 4096;
            gll16(kq,       Kd);     gll16(kq + 512, Kd + 512);
            gll16(vq,       Vd);     gll16(vq2,      Vd + 512);
        }
        cur ^= 1;

        if (wq + 31 < kbase) continue;   // wave fully masked (barrier already passed)

        // ---- QK^T:  S^T[key][q]  (scores pre-scaled via q) ----
        f32x16 sT[2];
#pragma unroll
        for (int kb2 = 0; kb2 < 2; ++kb2) {
#pragma unroll
            for (int j = 0; j < 16; ++j) sT[kb2][j] = 0.f;
            const int row = kb2 * 32 + c;
            const int sw  = row & 7;
#pragma unroll
            for (int dd = 0; dd < 4; ++dd) {
                short8 kf = *reinterpret_cast<const short8*>(
                    &Ksb[(row << 6) + (((2 * dd + h) ^ sw) << 3)]);
                sT[kb2] = __builtin_amdgcn_mfma_f32_32x32x16_bf16(
                    kf, qh[dd], sT[kb2], 0, 0, 0);
            }
        }

        // ---- fixed-zero-max softmax: p = exp2(s), accumulate l per lane ----
        const bool needmask = (kbase + KT - 1 > wq);
        float p[2][16];
        float s0 = 0.f, s1 = 0.f, s2 = 0.f, s3 = 0.f;
#pragma unroll
        for (int kb2 = 0; kb2 < 2; ++kb2)
#pragma unroll
            for (int r16 = 0; r16 < 16; ++r16) {
                float s = sT[kb2][r16];
                if (needmask) {
                    const int key = kbase + kb2 * 32 + (r16 & 3) + 8 * (r16 >> 2) + 4 * h;
                    if (key > qg) s = -INFINITY;
                }
                const float e = ex2(s);
                p[kb2][r16] = e;
                if      ((r16 & 3) == 0) s0 += e;
                else if ((r16 & 3) == 1) s1 += e;
                else if ((r16 & 3) == 2) s2 += e;
                else                     s3 += e;
            }
        lsum += (s0 + s1) + (s2 + s3);

        // ---- P -> bf16 (HW cvt_pk); B-frag = OWN values, register order ----
        unsigned wpk[2][8];
#pragma unroll
        for (int kb2 = 0; kb2 < 2; ++kb2)
#pragma unroll
            for (int i = 0; i < 8; ++i)
                wpk[kb2][i] = cvtpk(p[kb2][2 * i], p[kb2][2 * i + 1]);

        // ---- PV: A = V^T via dual ds_read_b64 (kappa map), B = own P ----
#pragma unroll
        for (int ks = 0; ks < 4; ++ks) {
            const int kb2 = ks >> 1;
            const int s2i = ks & 1;
            uint4v uw;
            uw.x = wpk[kb2][4 * s2i + 0];
            uw.y = wpk[kb2][4 * s2i + 1];
            uw.z = wpk[kb2][4 * s2i + 2];
            uw.w = wpk[kb2][4 * s2i + 3];
            short8 pa = __builtin_bit_cast(short8, uw);
#pragma unroll
            for (int dh = 0; dh < 2; ++dh) {
                const int row2 = dh * 32 + c;
                const int sw2  = row2 & 7;
                // keys 16ks+4h..+3 (granule 2ks) and 16ks+8+4h..+3 (granule 2ks+1)
                short4v lo = *reinterpret_cast<const short4v*>(
                    &Vtb[(row2 << 6) + (((2 * ks + 0) ^ sw2) << 3) + 4 * h]);
                short4v hi = *reinterpret_cast<const short4v*>(
                    &Vtb[(row2 << 6) + (((2 * ks + 1) ^ sw2) << 3) + 4 * h]);
                short8 vf;
                vf[0] = lo[0]; vf[1] = lo[1]; vf[2] = lo[2]; vf[3] = lo[3];
                vf[4] = hi[0]; vf[5] = hi[1]; vf[6] = hi[2]; vf[7] = hi[3];
                oT[dh] = __builtin_amdgcn_mfma_f32_32x32x16_bf16(
                    vf, pa, oT[dh], 0, 0, 0);
            }
        }
    }

    // ---- epilogue: combine h-halves, normalize, two-pass LDS transpose ----
    const float l = lsum + __shfl_xor(lsum, 32);
    const float inv  = (l > 0.f) ? (1.0f / l) : 0.f;
    if (h == 0)
        lseb[(size_t)par * BT + (size_t)b * TN + qg] =
            (l > 0.f) ? log2f(l) : -INFINITY;

    const int lr = 32 * (w & 1) + c;   // row within 64-row half
#pragma unroll
    for (int wh = 0; wh < 2; ++wh) {
        __syncthreads();               // first pass also drains stray prologue DMA
        if ((w >> 1) == wh) {
#pragma unroll
            for (int dh = 0; dh < 2; ++dh)
#pragma unroll
                for (int tq = 0; tq < 4; ++tq) {
                    const int g = 8 * dh + 2 * tq + h;       // d-granule 0..15
                    const int gs = g ^ (lr & 7);
                    f32x4 vv;
                    vv[0] = oT[dh][4 * tq + 0] * inv;
                    vv[1] = oT[dh][4 * tq + 1] * inv;
                    vv[2] = oT[dh][4 * tq + 2] * inv;
                    vv[3] = oT[dh][4 * tq + 3] * inv;
                    *reinterpret_cast<f32x4*>(&ep[(lr << 6) + (gs << 2)]) = vv;
                }
        }
        __syncthreads();
        {
            const int r2 = tid >> 2;           // 0..63
            const int q4 = tid & 3;
            u16* prow = pO + (size_t)par * BTH
                           + ((size_t)b * TN + qbase + 64 * wh + r2) * HN + 16 * q4;
            short8 sv[2];
#pragma unroll
            for (int i = 0; i < 4; ++i) {
                const int gs = (4 * q4 + i) ^ (r2 & 7);
                f32x4 vv = *reinterpret_cast<const f32x4*>(&ep[(r2 << 6) + (gs << 2)]);
#pragma unroll
                for (int j = 0; j < 4; ++j)
                    sv[i >> 1][(i & 1) * 4 + j] = (short)f2bf(vv[j]);
            }
            *reinterpret_cast<short8*>(prow)     = sv[0];
            *reinterpret_cast<short8*>(prow + 8) = sv[1];
        }
    }
}

// ---------------------------------------------------------------------------
// Kernel 3: merge the NSPLIT K-split partials.
// ---------------------------------------------------------------------------
template<int NSPLIT>
__global__ __launch_bounds__(256) void merge_k(
    const u16* __restrict__ pO,
    const float* __restrict__ lseb,
    float* __restrict__ out)
{
    const int gid = blockIdx.x * 256 + threadIdx.x;   // 0 .. 8*B*T-1
    const int row = gid >> 3;
    const int d0  = (gid & 7) * 8;

    float ls[NSPLIT];
    float M = -INFINITY;
#pragma unroll
    for (int i = 0; i < NSPLIT; ++i) {
        ls[i] = lseb[(size_t)i * BT + row];
        M = fmaxf(M, ls[i]);
    }
    float wv[NSPLIT];
    float den = 0.f;
#pragma unroll
    for (int i = 0; i < NSPLIT; ++i) {
        wv[i] = exp2f(ls[i] - M);      // exp2(-inf - M) = 0 for empty partials
        den += wv[i];
    }
    const float rden = 1.0f / den;

    f32x4 o0 = {0.f, 0.f, 0.f, 0.f}, o1 = {0.f, 0.f, 0.f, 0.f};
#pragma unroll
    for (int i = 0; i < NSPLIT; ++i) {
        short8 a = *reinterpret_cast<const short8*>(
            pO + (size_t)i * BTH + (size_t)row * HN + d0);
#pragma unroll
        for (int j = 0; j < 4; ++j) o0[j] += wv[i] * bf2f((u16)a[j]);
#pragma unroll
        for (int j = 0; j < 4; ++j) o1[j] += wv[i] * bf2f((u16)a[4 + j]);
    }
#pragma unroll
    for (int j = 0; j < 4; ++j) { o0[j] *= rden; o1[j] *= rden; }

    float* orow = out + (size_t)row * HN + d0;
    *reinterpret_cast<f32x4*>(orow)     = o0;
    *reinterpret_cast<f32x4*>(orow + 4) = o1;
}

// ---------------------------------------------------------------------------
extern "C" void kernel_launch(void* const* d_in, const int* in_sizes, int n_in,
                              void* d_out, int out_size, void* d_ws, size_t ws_size,
                              hipStream_t stream) {
    const float* x  = (const float*)d_in[0];
    const float* Wk = (const float*)d_in[1];
    const float* Wq = (const float*)d_in[2];
    const float* Wv = (const float*)d_in[3];
    float* out = (float*)d_out;

    // ws: q | k | vt (bf16) | pO (bf16, NSPLIT*BTH) | lse (f32, NSPLIT*BT)
    u16* qp   = (u16*)d_ws;
    u16* kp   = qp + BTH;
    u16* vtp  = kp + BTH;
    u16* pO   = vtp + BTH;

    qkv_proj<<<dim3(1024), dim3(256), 0, stream>>>(x, Wk, Wq, Wv, qp, kp, vtp);

    const size_t need4 = 7 * BTH * sizeof(u16) + 4 * BT * sizeof(float);
    if (ws_size >= need4) {
        float* lseb = (float*)(pO + 4 * BTH);
        attn_mfma<4><<<dim3(NQ * BN * 4), dim3(256), 0, stream>>>(qp, kp, vtp, pO, lseb);
        merge_k<4><<<dim3((unsigned)(8 * BT / 256)), dim3(256), 0, stream>>>(pO, lseb, out);
    } else {
        float* lseb = (float*)(pO + 2 * BTH);
        attn_mfma<2><<<dim3(NQ * BN * 2), dim3(256), 0, stream>>>(qp, kp, vtp, pO, lseb);
        merge_k<2><<<dim3((unsigned)(8 * BT / 256)), dim3(256), 0, stream>>>(pO, lseb, out);
    }
}

// Round 14
// 82.471 us; speedup vs baseline: 1.4096x; 1.4096x over previous
//
#include <hip/hip_runtime.h>
#include <hip/hip_bf16.h>
#include <math.h>

typedef short short8 __attribute__((ext_vector_type(8)));
typedef short short4v __attribute__((ext_vector_type(4)));
typedef float f32x4 __attribute__((ext_vector_type(4)));
typedef float f32x16 __attribute__((ext_vector_type(16)));
typedef unsigned int uint4v __attribute__((ext_vector_type(4)));
typedef unsigned short u16;

constexpr int TN = 4096;    // sequence
constexpr int CN = 32;      // embed
constexpr int HN = 64;      // head size
constexpr int QT = 128;     // q rows per block (4 waves x 32)
constexpr int KT = 64;      // keys per tile
constexpr int NQ = TN / QT; // 32 q-tiles per batch
constexpr int BN = 16;      // batch
constexpr size_t BT  = (size_t)BN * TN;
constexpr size_t BTH = BT * (size_t)HN;
constexpr float SCL = 0.18033688011112042f;  // 0.125 * log2(e), folded into q

__device__ __forceinline__ u16 f2bf(float f) {
    return __builtin_bit_cast(u16, __float2bfloat16(f));
}
__device__ __forceinline__ float bf2f(u16 v) {
    return __builtin_bit_cast(float, (unsigned)v << 16);
}
// HW packed f32->bf16 (RNE), src0 -> low half
__device__ __forceinline__ unsigned cvtpk(float lo, float hi) {
    unsigned r;
    asm("v_cvt_pk_bf16_f32 %0, %1, %2" : "=v"(r) : "v"(lo), "v"(hi));
    return r;
}
__device__ __forceinline__ float ex2(float x) {
#if __has_builtin(__builtin_amdgcn_exp2f)
    return __builtin_amdgcn_exp2f(x);   // raw v_exp_f32; exp2(-inf)=0
#else
    return exp2f(x);
#endif
}
// async global->LDS, 16B/lane, LDS dest = wave-uniform base + lane*16
typedef const __attribute__((address_space(1))) unsigned gu32;
typedef __attribute__((address_space(3))) unsigned lu32;
__device__ __forceinline__ void gll16(const u16* g, u16* l) {
    __builtin_amdgcn_global_load_lds((gu32*)(const void*)g, (lu32*)(void*)l, 16, 0, 0);
}

// ---------------------------------------------------------------------------
// Kernel 1: fused QKV projection -> bf16.  BYTE-IDENTICAL to green R12/R8.
// q PRE-SCALED by 0.125*log2(e).  q,k row-major; v transposed vt[b][h][t]
// (natural key order -- NO layout permutation).
// ---------------------------------------------------------------------------
__global__ __launch_bounds__(256) void qkv_proj(
    const float* __restrict__ x,
    const float* __restrict__ Wk,
    const float* __restrict__ Wq,
    const float* __restrict__ Wv,
    u16* __restrict__ qb, u16* __restrict__ kb, u16* __restrict__ vtb)
{
    __shared__ float sW[3][CN * HN];   // 24 KB: 0=q, 1=k, 2=v

    const int tid = threadIdx.x;
#pragma unroll
    for (int i = 0; i < 8; ++i) {
        const int idx = i * 256 + tid;   // 0..2047
        sW[0][idx] = Wq[idx];
        sW[1][idx] = Wk[idx];
        sW[2][idx] = Wv[idx];
    }
    __syncthreads();

    const int gid  = blockIdx.x * 256 + tid;   // 0 .. 4*B*T-1
    const int row  = gid >> 2;                 // b*T + t
    const int qq   = gid & 3;                  // h-quarter
    const int h0   = qq * 16;
    const int b    = row >> 12;                // T = 4096
    const int tloc = row & (TN - 1);
    const float* xr = x + (size_t)row * CN;

    float xv[CN];
#pragma unroll
    for (int cc = 0; cc < CN; cc += 4) {
        f32x4 t4 = *reinterpret_cast<const f32x4*>(xr + cc);
        xv[cc] = t4[0]; xv[cc + 1] = t4[1]; xv[cc + 2] = t4[2]; xv[cc + 3] = t4[3];
    }

    float aq[16], ak[16], av[16];
#pragma unroll
    for (int j = 0; j < 16; ++j) { aq[j] = 0.f; ak[j] = 0.f; av[j] = 0.f; }

#pragma unroll
    for (int cc = 0; cc < CN; ++cc) {
        const float xc = xv[cc];
        const float* wq = &sW[0][cc * HN + h0];
        const float* wk = &sW[1][cc * HN + h0];
        const float* wv = &sW[2][cc * HN + h0];
#pragma unroll
        for (int j = 0; j < 16; ++j) {
            aq[j] += xc * wq[j];
            ak[j] += xc * wk[j];
            av[j] += xc * wv[j];
        }
    }

    u16* qo = qb + (size_t)row * HN + h0;
    u16* ko = kb + (size_t)row * HN + h0;
#pragma unroll
    for (int v8 = 0; v8 < 2; ++v8) {
        short8 pq, pk;
#pragma unroll
        for (int j = 0; j < 8; ++j) {
            pq[j] = (short)f2bf(aq[v8 * 8 + j] * SCL);   // fold softmax scale
            pk[j] = (short)f2bf(ak[v8 * 8 + j]);
        }
        *reinterpret_cast<short8*>(qo + v8 * 8) = pq;
        *reinterpret_cast<short8*>(ko + v8 * 8) = pk;
    }
#pragma unroll
    for (int j = 0; j < 16; ++j)
        vtb[((size_t)b * HN + h0 + j) * TN + tloc] = f2bf(av[j]);
}

// ---------------------------------------------------------------------------
// Kernel 2: causal flash attention, 32x32x16 bf16 MFMA, fixed-zero-max
// softmax, NSPLIT-way K-split, LPT heavy-first 1-D grid.
// R14 = R13 with launch_bounds RESTORED to (256,4).  Single-variable bisect:
// R13's regression was pure (256,5) spill (VGPR 48, FETCH 29->61MB,
// WRITE 38->98MB); the dual-b64 shuffle-free PV itself passed replay.
//
// SHUFFLE-FREE PV via dual-b64 A-reads, natural V layout:
//   shared slot->key map kappa(j,h) = 16ks + 8*(j>>2) + 4h + (j&3).
//   B-frag = lane's OWN wpk words in register order; A-frag = two
//   ds_read_b64 chunks of the unchanged swizzled V^T tile (granule 2ks+g',
//   byte sub-offset 8h).  A/B share kappa -> sigma-invariant correct.
//   Deletes 8 bpermute + 24 cndmask per tile vs R12.
// ---------------------------------------------------------------------------
template<int NSPLIT>
__global__ __launch_bounds__(256, 4) void attn_mfma(
    const u16* __restrict__ qb,
    const u16* __restrict__ kb,
    const u16* __restrict__ vtb,
    u16* __restrict__ pO,
    float* __restrict__ lseb)
{
    __shared__ __align__(16) u16 smem[16384];   // 32 KB: buf b at b*8192 (K|Vt)
    float* ep = (float*)smem;                   // epilogue [64][64] f32 (16 KB)

    const int tid  = threadIdx.x;
    const int lane = tid & 63;
    const int w    = tid >> 6;
    const int c    = lane & 31;
    const int h    = lane >> 5;

    // LPT heavy-first mapping: idx 0.. -> qt NQ-1 .. 0
    const int idx = blockIdx.x;
    const int qt  = NQ - 1 - idx / (BN * NSPLIT);
    const int sub = idx % (BN * NSPLIT);
    const int b   = sub / NSPLIT;
    const int par = sub % NSPLIT;

    const int qbase = qt * QT;
    const int wq    = qbase + w * 32;
    const int qg    = wq + c;          // this lane's q row

    const u16* Qg = qb  + (size_t)b * TN * HN;
    const u16* Kg = kb  + (size_t)b * TN * HN;
    const u16* Vg = vtb + (size_t)b * HN * TN;

    // Q fragments: qh[dd] = Q[qg][(2*dd+h)*8 .. +7]
    short8 qh[4];
#pragma unroll
    for (int dd = 0; dd < 4; ++dd)
        qh[dd] = *reinterpret_cast<const short8*>(
            Qg + (size_t)qg * HN + (2 * dd + h) * 8);

    f32x16 oT[2];                      // O^T acc: col=q=c (lane-local)
#pragma unroll
    for (int dh = 0; dh < 2; ++dh)
#pragma unroll
        for (int j = 0; j < 16; ++j) oT[dh][j] = 0.f;
    float lsum = 0.f;

    const int nt = 2 * qt + 2;

    // ---- global_load_lds source pointers (pre-swizzled column) ----
    const int rw  = lane >> 3;                       // 0..7
    const int gsw = (lane & 7) ^ rw;                 // pre-swizzled granule
    const u16* kq  = Kg + (size_t)(par * KT + 16 * w + rw) * HN + gsw * 8;
    const u16* vq  = Vg + (size_t)(16 * w + rw) * TN + par * KT + gsw * 8;
    const u16* vq2 = vq + (size_t)8 * TN;
    const size_t kinc = (size_t)NSPLIT * KT * HN;    // u16 elements
    const size_t vinc = (size_t)NSPLIT * KT;

    // prologue: stage first tile into buf 0
    {
        u16* Kd = smem + w * 1024;
        u16* Vd = Kd + 4096;
        gll16(kq,        Kd);        gll16(kq + 512,  Kd + 512);
        gll16(vq,        Vd);        gll16(vq2,       Vd + 512);
    }

    int cur = 0;
    for (int t = par; t < nt; t += NSPLIT) {
        const int kbase = t * KT;

        __syncthreads();   // vmcnt drained -> buf[cur] ready; prev compute done
        u16* Ksb = smem + cur * 8192;
        u16* Vtb = Ksb + 4096;

        // prefetch next residue-tile into the other buffer
        if (t + NSPLIT < nt) {
            kq += kinc; vq += vinc; vq2 += vinc;
            u16* Kd = smem + (cur ^ 1) * 8192 + w * 1024;
            u16* Vd = Kd + 4096;
            gll16(kq,       Kd);     gll16(kq + 512, Kd + 512);
            gll16(vq,       Vd);     gll16(vq2,      Vd + 512);
        }
        cur ^= 1;

        if (wq + 31 < kbase) continue;   // wave fully masked (barrier already passed)

        // ---- QK^T:  S^T[key][q]  (scores pre-scaled via q) ----
        f32x16 sT[2];
#pragma unroll
        for (int kb2 = 0; kb2 < 2; ++kb2) {
#pragma unroll
            for (int j = 0; j < 16; ++j) sT[kb2][j] = 0.f;
            const int row = kb2 * 32 + c;
            const int sw  = row & 7;
#pragma unroll
            for (int dd = 0; dd < 4; ++dd) {
                short8 kf = *reinterpret_cast<const short8*>(
                    &Ksb[(row << 6) + (((2 * dd + h) ^ sw) << 3)]);
                sT[kb2] = __builtin_amdgcn_mfma_f32_32x32x16_bf16(
                    kf, qh[dd], sT[kb2], 0, 0, 0);
            }
        }

        // ---- fixed-zero-max softmax: p = exp2(s), accumulate l per lane ----
        const bool needmask = (kbase + KT - 1 > wq);
        float p[2][16];
        float s0 = 0.f, s1 = 0.f, s2 = 0.f, s3 = 0.f;
#pragma unroll
        for (int kb2 = 0; kb2 < 2; ++kb2)
#pragma unroll
            for (int r16 = 0; r16 < 16; ++r16) {
                float s = sT[kb2][r16];
                if (needmask) {
                    const int key = kbase + kb2 * 32 + (r16 & 3) + 8 * (r16 >> 2) + 4 * h;
                    if (key > qg) s = -INFINITY;
                }
                const float e = ex2(s);
                p[kb2][r16] = e;
                if      ((r16 & 3) == 0) s0 += e;
                else if ((r16 & 3) == 1) s1 += e;
                else if ((r16 & 3) == 2) s2 += e;
                else                     s3 += e;
            }
        lsum += (s0 + s1) + (s2 + s3);

        // ---- P -> bf16 (HW cvt_pk); B-frag = OWN values, register order ----
        unsigned wpk[2][8];
#pragma unroll
        for (int kb2 = 0; kb2 < 2; ++kb2)
#pragma unroll
            for (int i = 0; i < 8; ++i)
                wpk[kb2][i] = cvtpk(p[kb2][2 * i], p[kb2][2 * i + 1]);

        // ---- PV: A = V^T via dual ds_read_b64 (kappa map), B = own P ----
#pragma unroll
        for (int ks = 0; ks < 4; ++ks) {
            const int kb2 = ks >> 1;
            const int s2i = ks & 1;
            uint4v uw;
            uw.x = wpk[kb2][4 * s2i + 0];
            uw.y = wpk[kb2][4 * s2i + 1];
            uw.z = wpk[kb2][4 * s2i + 2];
            uw.w = wpk[kb2][4 * s2i + 3];
            short8 pa = __builtin_bit_cast(short8, uw);
#pragma unroll
            for (int dh = 0; dh < 2; ++dh) {
                const int row2 = dh * 32 + c;
                const int sw2  = row2 & 7;
                // keys 16ks+4h..+3 (granule 2ks) and 16ks+8+4h..+3 (granule 2ks+1)
                short4v lo = *reinterpret_cast<const short4v*>(
                    &Vtb[(row2 << 6) + (((2 * ks + 0) ^ sw2) << 3) + 4 * h]);
                short4v hi = *reinterpret_cast<const short4v*>(
                    &Vtb[(row2 << 6) + (((2 * ks + 1) ^ sw2) << 3) + 4 * h]);
                short8 vf;
                vf[0] = lo[0]; vf[1] = lo[1]; vf[2] = lo[2]; vf[3] = lo[3];
                vf[4] = hi[0]; vf[5] = hi[1]; vf[6] = hi[2]; vf[7] = hi[3];
                oT[dh] = __builtin_amdgcn_mfma_f32_32x32x16_bf16(
                    vf, pa, oT[dh], 0, 0, 0);
            }
        }
    }

    // ---- epilogue: combine h-halves, normalize, two-pass LDS transpose ----
    const float l = lsum + __shfl_xor(lsum, 32);
    const float inv  = (l > 0.f) ? (1.0f / l) : 0.f;
    if (h == 0)
        lseb[(size_t)par * BT + (size_t)b * TN + qg] =
            (l > 0.f) ? log2f(l) : -INFINITY;

    const int lr = 32 * (w & 1) + c;   // row within 64-row half
#pragma unroll
    for (int wh = 0; wh < 2; ++wh) {
        __syncthreads();               // first pass also drains stray prologue DMA
        if ((w >> 1) == wh) {
#pragma unroll
            for (int dh = 0; dh < 2; ++dh)
#pragma unroll
                for (int tq = 0; tq < 4; ++tq) {
                    const int g = 8 * dh + 2 * tq + h;       // d-granule 0..15
                    const int gs = g ^ (lr & 7);
                    f32x4 vv;
                    vv[0] = oT[dh][4 * tq + 0] * inv;
                    vv[1] = oT[dh][4 * tq + 1] * inv;
                    vv[2] = oT[dh][4 * tq + 2] * inv;
                    vv[3] = oT[dh][4 * tq + 3] * inv;
                    *reinterpret_cast<f32x4*>(&ep[(lr << 6) + (gs << 2)]) = vv;
                }
        }
        __syncthreads();
        {
            const int r2 = tid >> 2;           // 0..63
            const int q4 = tid & 3;
            u16* prow = pO + (size_t)par * BTH
                           + ((size_t)b * TN + qbase + 64 * wh + r2) * HN + 16 * q4;
            short8 sv[2];
#pragma unroll
            for (int i = 0; i < 4; ++i) {
                const int gs = (4 * q4 + i) ^ (r2 & 7);
                f32x4 vv = *reinterpret_cast<const f32x4*>(&ep[(r2 << 6) + (gs << 2)]);
#pragma unroll
                for (int j = 0; j < 4; ++j)
                    sv[i >> 1][(i & 1) * 4 + j] = (short)f2bf(vv[j]);
            }
            *reinterpret_cast<short8*>(prow)     = sv[0];
            *reinterpret_cast<short8*>(prow + 8) = sv[1];
        }
    }
}

// ---------------------------------------------------------------------------
// Kernel 3: merge the NSPLIT K-split partials.
// ---------------------------------------------------------------------------
template<int NSPLIT>
__global__ __launch_bounds__(256) void merge_k(
    const u16* __restrict__ pO,
    const float* __restrict__ lseb,
    float* __restrict__ out)
{
    const int gid = blockIdx.x * 256 + threadIdx.x;   // 0 .. 8*B*T-1
    const int row = gid >> 3;
    const int d0  = (gid & 7) * 8;

    float ls[NSPLIT];
    float M = -INFINITY;
#pragma unroll
    for (int i = 0; i < NSPLIT; ++i) {
        ls[i] = lseb[(size_t)i * BT + row];
        M = fmaxf(M, ls[i]);
    }
    float wv[NSPLIT];
    float den = 0.f;
#pragma unroll
    for (int i = 0; i < NSPLIT; ++i) {
        wv[i] = exp2f(ls[i] - M);      // exp2(-inf - M) = 0 for empty partials
        den += wv[i];
    }
    const float rden = 1.0f / den;

    f32x4 o0 = {0.f, 0.f, 0.f, 0.f}, o1 = {0.f, 0.f, 0.f, 0.f};
#pragma unroll
    for (int i = 0; i < NSPLIT; ++i) {
        short8 a = *reinterpret_cast<const short8*>(
            pO + (size_t)i * BTH + (size_t)row * HN + d0);
#pragma unroll
        for (int j = 0; j < 4; ++j) o0[j] += wv[i] * bf2f((u16)a[j]);
#pragma unroll
        for (int j = 0; j < 4; ++j) o1[j] += wv[i] * bf2f((u16)a[4 + j]);
    }
#pragma unroll
    for (int j = 0; j < 4; ++j) { o0[j] *= rden; o1[j] *= rden; }

    float* orow = out + (size_t)row * HN + d0;
    *reinterpret_cast<f32x4*>(orow)     = o0;
    *reinterpret_cast<f32x4*>(orow + 4) = o1;
}

// ---------------------------------------------------------------------------
extern "C" void kernel_launch(void* const* d_in, const int* in_sizes, int n_in,
                              void* d_out, int out_size, void* d_ws, size_t ws_size,
                              hipStream_t stream) {
    const float* x  = (const float*)d_in[0];
    const float* Wk = (const float*)d_in[1];
    const float* Wq = (const float*)d_in[2];
    const float* Wv = (const float*)d_in[3];
    float* out = (float*)d_out;

    // ws: q | k | vt (bf16) | pO (bf16, NSPLIT*BTH) | lse (f32, NSPLIT*BT)
    u16* qp   = (u16*)d_ws;
    u16* kp   = qp + BTH;
    u16* vtp  = kp + BTH;
    u16* pO   = vtp + BTH;

    qkv_proj<<<dim3(1024), dim3(256), 0, stream>>>(x, Wk, Wq, Wv, qp, kp, vtp);

    const size_t need4 = 7 * BTH * sizeof(u16) + 4 * BT * sizeof(float);
    if (ws_size >= need4) {
        float* lseb = (float*)(pO + 4 * BTH);
        attn_mfma<4><<<dim3(NQ * BN * 4), dim3(256), 0, stream>>>(qp, kp, vtp, pO, lseb);
        merge_k<4><<<dim3((unsigned)(8 * BT / 256)), dim3(256), 0, stream>>>(pO, lseb, out);
    } else {
        float* lseb = (float*)(pO + 2 * BTH);
        attn_mfma<2><<<dim3(NQ * BN * 2), dim3(256), 0, stream>>>(qp, kp, vtp, pO, lseb);
        merge_k<2><<<dim3((unsigned)(8 * BT / 256)), dim3(256), 0, stream>>>(pO, lseb, out);
    }
}